// Round 5
// baseline (3618.917 us; speedup 1.0000x reference)
//
#include <hip/hip_runtime.h>
#include <stdint.h>

// GGNN, fully collapsed:
//   s_t[n] = sum_{e: dst=n, type=t} x[src[e]]            (gather, fp32->bf16)
//   k_fused per 32-row slab:
//     gi = s @ Wc^T  (K=384, Wc = W_ih @ Wmsg_cat, hi/lo bf16)   [in-register]
//     gh = x @ W_hh^T (K=128, hi/lo bf16)                        [in-register]
//     x  = GRU(gi + typed-bias + b_ih, gh + b_hh, x)   fp32 master, fp32 gates
// MFMA C-layout alignment: wave w, subtile ct holds col ct*128 + w*32 + (lane&31)
// => one lane owns the (r,z,n) gate triplet for its feature j. No exchange needed.

typedef __bf16 bf16;
typedef __bf16 v8bf  __attribute__((ext_vector_type(8)));
typedef __bf16 v2bf  __attribute__((ext_vector_type(2)));
typedef float  v16f  __attribute__((ext_vector_type(16)));

__device__ __forceinline__ float sigf(float a){ return 1.0f/(1.0f+__expf(-a)); }

__global__ void k_diag(float* out, int n, float v){
  int i = threadIdx.x; if(i<n) out[i] = v;
}

__global__ void k_embed(const int* __restrict__ xtype, const int* __restrict__ xtok,
                        const float* __restrict__ xsmall,
                        const float* __restrict__ temb, const float* __restrict__ kemb,
                        float* __restrict__ x, int N){
  int n = blockIdx.x; int j = threadIdx.x;
  if(n>=N) return;
  float v;
  if(j<32)       v = temb[xtype[n]*32 + j];
  else if(j<64)  v = kemb[xtok[n]*32 + (j-32)];
  else           v = xsmall[(size_t)n*64 + (j-64)];
  x[(size_t)n*128 + j] = v;
}

// Wc[o2][K] = sum_k2 W_ih[o2,k2] * msg_W[K>>7][k2][K&127]
__global__ void k_wcomb(const float* __restrict__ W_ih, const float* __restrict__ msg_W,
                        float* __restrict__ Wc){
  int i = blockIdx.x*256 + threadIdx.x;
  if(i >= 147456) return;
  int o2 = i/384, K = i%384;
  const float* wr = W_ih + o2*128;
  const float* mc = msg_W + (K>>7)*16384 + (K&127);
  float acc = 0.f;
  #pragma unroll 4
  for(int k2=0;k2<128;k2++) acc += wr[k2]*mc[k2*128];
  Wc[i] = acc;
}

// mbp[t][o2] = sum_k2 W_ih[o2,k2]*msg_b[t,k2]
__global__ void k_mbp(const float* __restrict__ W_ih, const float* __restrict__ msg_b,
                      float* __restrict__ mbp){
  int i = blockIdx.x*256 + threadIdx.x;
  if(i >= 1152) return;
  int t = i/384, o2 = i%384;
  const float* wr = W_ih + o2*128;
  const float* mb = msg_b + t*128;
  float acc = 0.f;
  #pragma unroll 4
  for(int k2=0;k2<128;k2++) acc += wr[k2]*mb[k2];
  mbp[i] = acc;
}

// hi/lo split. layout: [0,147456) Wc [o=384][K=384]; [147456,196608) W_hh [o=384][k=128]
__global__ void k_wprep(const float* __restrict__ Wc, const float* __restrict__ W_hh,
                        bf16* __restrict__ Whi, bf16* __restrict__ Wlo){
  int i = blockIdx.x*256 + threadIdx.x;
  if(i >= 196608) return;
  float w = (i < 147456) ? Wc[i] : W_hh[i-147456];
  bf16 h = (bf16)w;
  float lo = w - (float)h;
  Whi[i] = h; Wlo[i] = (bf16)lo;
}

__global__ void k_hist3(const int* __restrict__ dst, const int* __restrict__ et,
                        int* __restrict__ deg3, int E){
  int e = blockIdx.x*blockDim.x + threadIdx.x;
  if(e<E) atomicAdd(&deg3[dst[e]*3 + et[e]], 1);
}

__global__ void k_scan1(const int* __restrict__ deg, int n, int* __restrict__ part, int* __restrict__ bsum){
  __shared__ int s[256];
  int t = threadIdx.x;
  int base = blockIdx.x*1024 + t*4;
  int v[4]; int sum=0;
  #pragma unroll
  for(int k=0;k<4;k++){ int i=base+k; int d=(i<n)?deg[i]:0; sum+=d; v[k]=sum; }
  s[t]=sum; __syncthreads();
  for(int off=1;off<256;off<<=1){
    int add = (t>=off)? s[t-off] : 0;
    __syncthreads();
    s[t]+=add;
    __syncthreads();
  }
  int excl = (t>0)? s[t-1] : 0;
  #pragma unroll
  for(int k=0;k<4;k++){ int i=base+k; if(i<n) part[i]=v[k]+excl; }
  if(t==255) bsum[blockIdx.x] = s[255];
}

__global__ void k_scan2(const int* __restrict__ bsum, int nb, int* __restrict__ carry){
  if(threadIdx.x==0 && blockIdx.x==0){
    int c=0;
    for(int b=0;b<nb;b++){ carry[b]=c; c+=bsum[b]; }
  }
}

__global__ void k_finalize(const int* __restrict__ part, const int* __restrict__ deg,
                           const int* __restrict__ carry, int n,
                           int* __restrict__ rowptr, int* __restrict__ cursor){
  int i = blockIdx.x*blockDim.x + threadIdx.x;
  if(i>=n) return;
  int incl = part[i] + carry[i>>10];
  rowptr[i+1] = incl;
  cursor[i] = incl - deg[i];
  if(i==0) rowptr[0]=0;
}

__global__ void k_fill3(const int* __restrict__ src, const int* __restrict__ dst,
                        const int* __restrict__ et, int* __restrict__ cursor,
                        int* __restrict__ pay, int E){
  int e = blockIdx.x*blockDim.x + threadIdx.x;
  if(e>=E) return;
  int pos = atomicAdd(&cursor[dst[e]*3 + et[e]], 1);
  pay[pos] = src[e];
}

// gather: s[n, t*128 + c] = sum over typed in-edges of x[src]; 4 nodes/block, 2 cols/lane
__global__ void k_gather3(const float* __restrict__ x, const int* __restrict__ rp3,
                          const int* __restrict__ pay, bf16* __restrict__ s, int N){
  int n = blockIdx.x*4 + (threadIdx.x>>6);
  if(n>=N) return;
  int lane = threadIdx.x & 63;
  int c = lane*2;
  int b = n*3;
  int e0=rp3[b], e1=rp3[b+1], e2=rp3[b+2], e3=rp3[b+3];
  float a0=0.f,b0=0.f,a1=0.f,b1=0.f,a2=0.f,b2=0.f;
  for(int i=e0;i<e1;i++){ float2 v = *(const float2*)&x[(size_t)pay[i]*128 + c]; a0+=v.x; b0+=v.y; }
  for(int i=e1;i<e2;i++){ float2 v = *(const float2*)&x[(size_t)pay[i]*128 + c]; a1+=v.x; b1+=v.y; }
  for(int i=e2;i<e3;i++){ float2 v = *(const float2*)&x[(size_t)pay[i]*128 + c]; a2+=v.x; b2+=v.y; }
  size_t o = (size_t)n*384 + c;
  v2bf t;
  t[0]=(bf16)a0; t[1]=(bf16)b0; *(v2bf*)&s[o]       = t;
  t[0]=(bf16)a1; t[1]=(bf16)b1; *(v2bf*)&s[o+128]   = t;
  t[0]=(bf16)a2; t[1]=(bf16)b2; *(v2bf*)&s[o+256]   = t;
}

// Fused gi-GEMM + gh-GEMM + GRU per 32-row slab. 256 threads = 4 waves.
// Wave w covers output cols {ct*128 + w*32 + lrow : ct=0..2} for gi AND gh.
#define ASTR 392   // 384+8: 16B-aligned rows, bank stride 4 (4-way, acceptable)
#define XSTR 136
#define BSTR 72
__global__ __launch_bounds__(256) void k_fused(
    const bf16* __restrict__ s, float* __restrict__ x, int M,
    const bf16* __restrict__ Whi, const bf16* __restrict__ Wlo,
    const int* __restrict__ deg3, const float* __restrict__ mbp,
    const float* __restrict__ b_ih, const float* __restrict__ b_hh)
{
  __shared__ bf16 As[32*ASTR];   // s rows   (25.1 KB)
  __shared__ bf16 Ax[32*XSTR];   // x rows   ( 8.7 KB)
  __shared__ bf16 Bs[128*BSTR];  // W slice  (18.4 KB)
  int tid = threadIdx.x, lane = tid & 63, wave = tid >> 6;
  int row0 = blockIdx.x * 32;
  int lrow = lane & 31, lk8 = (lane>>5)*8;

  // stage s: 32x384 -> 1536 v8 chunks (6/thread)
  #pragma unroll
  for(int p=0;p<6;p++){
    int ch = tid + p*256;
    int row = ch/48, c8 = (ch%48)*8;
    int gr = row0 + row; if(gr>=M) gr = M-1;
    *(v8bf*)&As[row*ASTR + c8] = *(const v8bf*)(s + (size_t)gr*384 + c8);
  }
  // stage x (fp32->bf16): 32x128 -> 512 chunks (2/thread)
  #pragma unroll
  for(int p=0;p<2;p++){
    int ch = tid + p*256;
    int row = ch>>4, c8 = (ch&15)*8;
    int gr = row0 + row; if(gr>=M) gr = M-1;
    const float* ap = x + (size_t)gr*128 + c8;
    float4 f0 = *(const float4*)ap;
    float4 f1 = *(const float4*)(ap+4);
    v8bf t;
    t[0]=(bf16)f0.x; t[1]=(bf16)f0.y; t[2]=(bf16)f0.z; t[3]=(bf16)f0.w;
    t[4]=(bf16)f1.x; t[5]=(bf16)f1.y; t[6]=(bf16)f1.z; t[7]=(bf16)f1.w;
    *(v8bf*)&Ax[row*XSTR + c8] = t;
  }

  v16f gacc[6] = {};   // [0..2] gi ct0..2, [3..5] gh ct0..2

  for(int ct=0; ct<3; ct++){
    int colb = ct*128;
    // ---- gi: A=As (K=384), B=Wc rows [colb, colb+128), hi then lo pass ----
    #pragma unroll
    for(int pass=0; pass<2; pass++){
      const bf16* Bp = (pass ? Wlo : Whi) + (size_t)colb*384;
      for(int k0=0; k0<384; k0+=64){
        __syncthreads();
        #pragma unroll
        for(int p=0;p<4;p++){
          int ch = tid + p*256;
          int col = ch>>3, c8 = (ch&7)*8;
          *(v8bf*)&Bs[col*BSTR + c8] = *(const v8bf*)(Bp + (size_t)col*384 + k0 + c8);
        }
        __syncthreads();
        #pragma unroll
        for(int ks=0;ks<4;ks++){
          int kb = ks*16 + lk8;
          v8bf a = *(const v8bf*)&As[lrow*ASTR + k0 + kb];
          v8bf b = *(const v8bf*)&Bs[(wave*32 + lrow)*BSTR + kb];
          gacc[ct] = __builtin_amdgcn_mfma_f32_32x32x16_bf16(a, b, gacc[ct], 0,0,0);
        }
      }
    }
    // ---- gh: A=Ax (K=128), B=W_hh rows [colb, colb+128) ----
    #pragma unroll
    for(int pass=0; pass<2; pass++){
      const bf16* Bp = (pass ? Wlo : Whi) + 147456 + (size_t)colb*128;
      for(int k0=0; k0<128; k0+=64){
        __syncthreads();
        #pragma unroll
        for(int p=0;p<4;p++){
          int ch = tid + p*256;
          int col = ch>>3, c8 = (ch&7)*8;
          *(v8bf*)&Bs[col*BSTR + c8] = *(const v8bf*)(Bp + (size_t)col*128 + k0 + c8);
        }
        __syncthreads();
        #pragma unroll
        for(int ks=0;ks<4;ks++){
          int kb = ks*16 + lk8;
          v8bf a = *(const v8bf*)&Ax[lrow*XSTR + k0 + kb];
          v8bf b = *(const v8bf*)&Bs[(wave*32 + lrow)*BSTR + kb];
          gacc[3+ct] = __builtin_amdgcn_mfma_f32_32x32x16_bf16(a, b, gacc[3+ct], 0,0,0);
        }
      }
    }
  }

  // ---- GRU epilogue, fully in-register. j = feature index of this lane. ----
  int j = wave*32 + lrow;
  float bi0 = b_ih[j],     bh0 = b_hh[j];
  float bi1 = b_ih[128+j], bh1 = b_hh[128+j];
  float bi2 = b_ih[256+j], bh2 = b_hh[256+j];
  float mb[3][3];
  #pragma unroll
  for(int t=0;t<3;t++){
    mb[t][0] = mbp[t*384 + j];
    mb[t][1] = mbp[t*384 + 128 + j];
    mb[t][2] = mbp[t*384 + 256 + j];
  }
  int rq4 = 4*(lane>>5);
  #pragma unroll
  for(int r=0;r<16;r++){
    int gr = row0 + (r&3) + 8*(r>>2) + rq4;
    if(gr >= M) continue;
    const int* dq = &deg3[gr*3];
    float d0 = (float)dq[0], d1 = (float)dq[1], d2 = (float)dq[2];
    float ir  = gacc[0][r] + bi0 + d0*mb[0][0] + d1*mb[1][0] + d2*mb[2][0];
    float iz  = gacc[1][r] + bi1 + d0*mb[0][1] + d1*mb[1][1] + d2*mb[2][1];
    float in_ = gacc[2][r] + bi2 + d0*mb[0][2] + d1*mb[1][2] + d2*mb[2][2];
    float hr  = gacc[3][r] + bh0;
    float hz  = gacc[4][r] + bh1;
    float hn  = gacc[5][r] + bh2;
    float rg = sigf(ir+hr);
    float zg = sigf(iz+hz);
    float nn = tanhf(in_ + rg*hn);
    float xo = x[(size_t)gr*128 + j];
    x[(size_t)gr*128 + j] = (1.f - zg)*nn + zg*xo;
  }
}

__device__ __forceinline__ int lb_batch(const int* __restrict__ batch, int N, int g){
  int lo=0, hi=N;
  while(lo<hi){ int mid=(lo+hi)>>1; if(batch[mid]<g) lo=mid+1; else hi=mid; }
  return lo;
}

__global__ void k_pool2(const float* __restrict__ x, const int* __restrict__ batch,
                        float* __restrict__ pooled, int N){
  int g = blockIdx.x, slice = blockIdx.y;
  int j = threadIdx.x;
  int lo = lb_batch(batch,N,g), hi = lb_batch(batch,N,g+1);
  float acc = 0.f;
  for(int r=lo+slice; r<hi; r+=32) acc += x[(size_t)r*128 + j];
  atomicAdd(&pooled[g*128+j], acc);
}

__global__ void k_head(const float* __restrict__ pooled, const int* __restrict__ batch, int N,
                       const float* __restrict__ W1, const float* __restrict__ b1,
                       const float* __restrict__ W2, const float* __restrict__ b2,
                       float* __restrict__ out){
  int g = blockIdx.x; int j = threadIdx.x;
  __shared__ float p[128];
  __shared__ float red[128];
  int lo = lb_batch(batch,N,g), hi = lb_batch(batch,N,g+1);
  float c = (float)(hi-lo); if(c < 1.f) c = 1.f;
  p[j] = pooled[g*128+j] / c;
  __syncthreads();
  float acc = b1[j];
  #pragma unroll 4
  for(int i=0;i<128;i++) acc += W1[j*128+i]*p[i];
  float v = (acc>0.f?acc:0.f) * W2[j];
  red[j] = v; __syncthreads();
  for(int s=64;s>0;s>>=1){ if(j<s) red[j]+=red[j+s]; __syncthreads(); }
  if(j==0) out[g] = red[0] + b2[0];
}

extern "C" void kernel_launch(void* const* d_in, const int* in_sizes, int n_in,
                              void* d_out, int out_size, void* d_ws, size_t ws_size,
                              hipStream_t stream){
  const int*   x_type    = (const int*)d_in[0];
  const int*   x_tok     = (const int*)d_in[1];
  const float* x_small   = (const float*)d_in[2];
  const int*   edge_index= (const int*)d_in[3];
  const int*   edge_type = (const int*)d_in[4];
  const int*   batch     = (const int*)d_in[5];
  const float* type_emb  = (const float*)d_in[6];
  const float* tok_emb   = (const float*)d_in[7];
  const float* msg_W     = (const float*)d_in[8];
  const float* msg_b     = (const float*)d_in[9];
  const float* W_ih      = (const float*)d_in[10];
  const float* W_hh      = (const float*)d_in[11];
  const float* b_ih      = (const float*)d_in[12];
  const float* b_hh      = (const float*)d_in[13];
  const float* pW1       = (const float*)d_in[14];
  const float* pb1       = (const float*)d_in[15];
  const float* pW2       = (const float*)d_in[16];
  const float* pb2       = (const float*)d_in[17];
  float* out = (float*)d_out;

  int N = in_sizes[0];
  int E = in_sizes[3]/2;
  const int* src = edge_index;
  const int* dst = edge_index + E;
  int n3 = 3*N;
  int nch = (n3+1023)/1024;

  char* w = (char*)d_ws;
  size_t off = 0;
  auto alloc = [&](size_t bytes)->char*{ char* p = w + off; off += (bytes + 511) & ~511ull; return p; };
  float* x      = (float*)alloc((size_t)N*128*4);     // fp32 master state (51.2 MB)
  bf16*  s      = (bf16*)alloc((size_t)N*384*2);      // gathered sums     (76.8 MB)
  int*   deg3   = (int*)alloc((size_t)n3*4);
  int*   part   = (int*)alloc((size_t)n3*4);
  int*   rp3    = (int*)alloc((size_t)(n3+1)*4);
  int*   cursor = (int*)alloc((size_t)n3*4);
  int*   pay    = (int*)alloc((size_t)E*4);
  int*   bsum   = (int*)alloc((size_t)nch*4);
  int*   carry  = (int*)alloc((size_t)nch*4);
  float* Wc     = (float*)alloc((size_t)147456*4);
  bf16*  Whi    = (bf16*)alloc((size_t)196608*2);
  bf16*  Wlo    = (bf16*)alloc((size_t)196608*2);
  float* mbp    = (float*)alloc((size_t)1152*4);
  float* pooled = (float*)alloc(64*128*4);
  if(off > ws_size){
    k_diag<<<1,64,0,stream>>>(out, out_size, 1.0e6f + (float)(ws_size>>20));
    return;
  }

  const int tb = 256;
  hipMemsetAsync(deg3, 0, (size_t)n3*4, stream);
  k_wcomb   <<<576, 256, 0, stream>>>(W_ih, msg_W, Wc);
  k_mbp     <<<5, 256, 0, stream>>>(W_ih, msg_b, mbp);
  k_wprep   <<<768, 256, 0, stream>>>(Wc, W_hh, Whi, Wlo);
  k_hist3   <<<(E+tb-1)/tb, tb, 0, stream>>>(dst, edge_type, deg3, E);
  k_scan1   <<<nch, 256, 0, stream>>>(deg3, n3, part, bsum);
  k_scan2   <<<1, 64, 0, stream>>>(bsum, nch, carry);
  k_finalize<<<(n3+tb-1)/tb, tb, 0, stream>>>(part, deg3, carry, n3, rp3, cursor);
  k_fill3   <<<(E+tb-1)/tb, tb, 0, stream>>>(src, dst, edge_type, cursor, pay, E);
  k_embed   <<<N, 128, 0, stream>>>(x_type, x_tok, x_small, type_emb, tok_emb, x, N);

  for(int it=0; it<8; it++){
    k_gather3<<<(N+3)/4, 256, 0, stream>>>(x, rp3, pay, s, N);
    k_fused  <<<(N+31)/32, 256, 0, stream>>>(s, x, N, Whi, Wlo, deg3, mbp, b_ih, b_hh);
  }
  hipMemsetAsync(pooled, 0, 64*128*4, stream);
  k_pool2<<<dim3(64,32), 128, 0, stream>>>(x, batch, pooled, N);
  k_head <<<64, 128, 0, stream>>>(pooled, batch, N, pW1, pb1, pW2, pb2, out);
}